// Round 2
// baseline (378.573 us; speedup 1.0000x reference)
//
#include <hip/hip_runtime.h>
#include <math.h>

typedef __bf16 bf16x8 __attribute__((ext_vector_type(8)));
typedef float f32x4 __attribute__((ext_vector_type(4)));
typedef unsigned short u16;

__device__ __forceinline__ u16 f2b(float f) {
  // fp32 -> bf16 round-to-nearest-even (finite inputs only)
  unsigned u = __builtin_bit_cast(unsigned, f);
  u = (u + 0x7fffu + ((u >> 16) & 1u)) >> 16;
  return (u16)u;
}

__device__ __forceinline__ f32x4 mfma16(bf16x8 a, bf16x8 b, f32x4 c) {
  // D[i][j] = sum_k A[i][k]*B[j][k]; frag: lane holds OP[lane&15][8*(lane>>4)..+8)
  // per K=32 step; D: col=lane&15 -> j, row=4*(lane>>4)+reg -> i
  return __builtin_amdgcn_mfma_f32_16x16x32_bf16(a, b, c, 0, 0, 0);
}

// XOR-swizzled LDS addressing: tiles are [rows][64 u16], 16B chunk index XORed
// with (row & 7). Keeps every b128 access 16B-aligned AND spreads the LD=64
// (32-dword) row-stride aliasing across banks.
__device__ __forceinline__ int sw(int r, int c) {      // element (u16) address
  return (r << 6) + ((((c >> 3) ^ r) & 7) << 3) + (c & 7);
}
__device__ __forceinline__ int swc(int r, int ch) {    // chunk (16B) address
  return (r << 6) + (((ch ^ r) & 7) << 3);
}

// Prep: UNswizzled bf16 weight image, rows of 64 u16 (128 B):
//   rows 0-47:  M_t[c'][c] = scale * sum_h Wq[c][h]*Wk[c'][h]   ((scale*Wq@Wk^T)^T)
//   rows 48-95: Wv_t[h][c] = Wv[c][h]
// cols 48-63 zeroed (K pad). head_main reads MFMA fragments for these rows
// straight from global: the 12 KB image is L1-resident after the first block
// on each CU, which removes the per-block LDS weight stage and its barrier.
__global__ __launch_bounds__(256) void head_prep(const float* __restrict__ Wq,
                                                 const float* __restrict__ Wk,
                                                 const float* __restrict__ Wv,
                                                 u16* __restrict__ ws) {
  __shared__ float wq[2304], wk[2304], wv[2304];
  const float scale = 0.14433756729740643f;  // 1/sqrt(48)
  for (int i = threadIdx.x; i < 2304; i += 256) {
    wq[i] = Wq[i];
    wk[i] = Wk[i];
    wv[i] = Wv[i];
  }
  __syncthreads();
  for (int idx = threadIdx.x; idx < 96 * 64; idx += 256) {
    int r = idx >> 6, c = idx & 63;
    float v = 0.f;
    if (c < 48) {
      if (r < 48) {
        float a = 0.f;
        for (int h = 0; h < 48; ++h) a += wq[c * 48 + h] * wk[r * 48 + h];
        v = a * scale;
      } else {
        v = wv[c * 48 + (r - 48)];
      }
    }
    ws[idx] = f2b(v);  // unswizzled: row r, col c
  }
}

// One workgroup (4 waves) per batch element; wave w owns t-rows [16w,16w+16).
// S is computed TRANSPOSED (S^T = X @ QM^T) so that:
//  - QM is produced as QM^T tiles -> vectorized ushort4 LDS writes (3/thread)
//  - softmax's reduction axis (s) is the D-fragment ROW axis: 15 in-lane ops
//    + 2 shuffles, instead of 4-level butterflies per register (32 swizzles)
//  - P rows are wave-private -> P overlays QM (not X) -> no third barrier.
// LDS regions (176 rows * 128 B = 22528 B):
//   QM/P: rows 0-63   (wave-private rows; QM^T written, read, overlaid by P)
//   X   : rows 64-127 (bf16 x, K-padded to 64)
//   VT  : rows 128-175 (V transposed, h-major / s-inner)
__global__ __launch_bounds__(256, 6) void head_main(const float* __restrict__ x,
                                                    const u16* __restrict__ wimg,
                                                    float* __restrict__ out) {
  __shared__ u16 lds[176 * 64];
  u16* const QM = lds;                // 64 rows (also P)
  u16* const X  = lds + 64 * 64;      // 64 rows
  u16* const VT = lds + 128 * 64;     // 48 rows

  const int tid  = threadIdx.x;
  const int lane = tid & 63;
  const int w    = tid >> 6;
  const int qd   = lane >> 4;
  const int col  = lane & 15;
  const long b   = blockIdx.x;

  // ---- stage OWN 16 x rows -> bf16 LDS (wave-contiguous float4 reads) ----
  {
    const float* xb = x + b * 3072 + w * 768;  // wave's 16 rows * 48 floats
#pragma unroll
    for (int it = 0; it < 3; ++it) {
      int e0 = lane * 4 + it * 256;   // element offset in the wave's 768 floats
      float4 v = *(const float4*)(xb + e0);
      int row = 16 * w + e0 / 48;
      int c0  = e0 % 48;              // multiple of 4 -> stays inside one chunk
      ushort4 pk;
      pk.x = f2b(v.x); pk.y = f2b(v.y); pk.z = f2b(v.z); pk.w = f2b(v.w);
      *(ushort4*)(X + sw(row, c0)) = pk;
    }
    // zero K-pad (cols 48..63) of own rows in X and QM: one ushort4 each
    ushort4 z = {0, 0, 0, 0};
    *(ushort4*)(X  + sw(16 * w + col, 48 + 4 * qd)) = z;
    *(ushort4*)(QM + sw(16 * w + col, 48 + 4 * qd)) = z;
  }
  __syncthreads();  // staging visible (proven round-0 discipline)

  // ---- own x fragments (A-rows t = 16w+col) ----
  const int ar = 16 * w + col;
  const bf16x8 xa0 = *(const bf16x8*)(X + swc(ar, qd));
  const bf16x8 xa1 = *(const bf16x8*)(X + swc(ar, qd + 4));

  // ---- projections, weights direct from global (L1-hit after block 0) ----
  // QM^T tile: D[c'][t] = sum_c M_t[c'][c] * x[t][c]  (M_t first operand)
  //   -> QM_lds[t=16w+col][c'=16n+4qd+i], i consecutive -> ushort4
  // V tile:    D[t][h]  = sum_c x[t][c] * Wv_t[h][c]   (x first operand)
  //   -> VT[h=16n+col][s=16w+4qd+i], i consecutive -> ushort4
#pragma unroll
  for (int n = 0; n < 3; ++n) {
    const u16* mrow = wimg + (16 * n + col) * 64;
    const u16* vrow = wimg + (48 + 16 * n + col) * 64;
    bf16x8 m0 = *(const bf16x8*)(mrow + 8 * qd);
    bf16x8 m1 = *(const bf16x8*)(mrow + 8 * qd + 32);
    bf16x8 v0 = *(const bf16x8*)(vrow + 8 * qd);
    bf16x8 v1 = *(const bf16x8*)(vrow + 8 * qd + 32);
    f32x4 aq = {0.f, 0.f, 0.f, 0.f};
    aq = mfma16(m0, xa0, aq);
    aq = mfma16(m1, xa1, aq);
    ushort4 pq;
    pq.x = f2b(aq[0]); pq.y = f2b(aq[1]); pq.z = f2b(aq[2]); pq.w = f2b(aq[3]);
    *(ushort4*)(QM + sw(16 * w + col, 16 * n + 4 * qd)) = pq;
    f32x4 av = {0.f, 0.f, 0.f, 0.f};
    av = mfma16(xa0, v0, av);
    av = mfma16(xa1, v1, av);
    ushort4 pv;
    pv.x = f2b(av[0]); pv.y = f2b(av[1]); pv.z = f2b(av[2]); pv.w = f2b(av[3]);
    *(ushort4*)(VT + sw(16 * n + col, 16 * w + 4 * qd)) = pv;
  }

  __syncthreads();  // X (all rows) + VT + QM complete for everyone

  // ---- S^T = X @ QM^T : D[s=16st+4qd+i][t=16w+col] ----
  float sv[4][4];
  {
    const bf16x8 qb0 = *(const bf16x8*)(QM + swc(ar, qd));
    const bf16x8 qb1 = *(const bf16x8*)(QM + swc(ar, qd + 4));
#pragma unroll
    for (int st = 0; st < 4; ++st) {
      const int br = 16 * st + col;
      f32x4 a = {0.f, 0.f, 0.f, 0.f};
      a = mfma16(*(const bf16x8*)(X + swc(br, qd)), qb0, a);
      a = mfma16(*(const bf16x8*)(X + swc(br, qd + 4)), qb1, a);
#pragma unroll
      for (int i = 0; i < 4; ++i) sv[st][i] = a[i];
    }
  }

  // ---- causal mask + softmax over s (row axis: in-lane + 2 shuffles) ----
  const int tg = 16 * w + col;
  float m = -INFINITY;
#pragma unroll
  for (int st = 0; st < 4; ++st)
#pragma unroll
    for (int i = 0; i < 4; ++i) {
      int sg = 16 * st + 4 * qd + i;
      float v = (sg <= tg) ? sv[st][i] : -INFINITY;
      sv[st][i] = v;
      m = fmaxf(m, v);
    }
  m = fmaxf(m, __shfl_xor(m, 16, 64));
  m = fmaxf(m, __shfl_xor(m, 32, 64));
  float l = 0.f;
#pragma unroll
  for (int st = 0; st < 4; ++st)
#pragma unroll
    for (int i = 0; i < 4; ++i) {
      float p = __expf(sv[st][i] - m);  // exp(-inf)=0 handles the mask
      sv[st][i] = p;
      l += p;
    }
  l += __shfl_xor(l, 16, 64);
  l += __shfl_xor(l, 32, 64);
  float rl = __builtin_amdgcn_rcpf(l);  // per-lane: 1/l for t = 16w+col

  // ---- write P' (unnormalized) over QM: own rows, vectorized ----
#pragma unroll
  for (int st = 0; st < 4; ++st) {
    ushort4 pk;
    pk.x = f2b(sv[st][0]); pk.y = f2b(sv[st][1]);
    pk.z = f2b(sv[st][2]); pk.w = f2b(sv[st][3]);
    *(ushort4*)(QM + sw(16 * w + col, 16 * st + 4 * qd)) = pk;
  }
  __threadfence_block();  // same-wave write->read ordering (wave-private rows)

  // ---- O = P' @ V (A = own P rows, B = VT rows), scale rows by 1/l ----
  f32x4 o0 = {0.f, 0.f, 0.f, 0.f}, o1 = o0, o2 = o0;
#pragma unroll
  for (int kt = 0; kt < 2; ++kt) {
    const int ch = qd + 4 * kt;
    bf16x8 pa = *(const bf16x8*)(QM + swc(ar, ch));
    o0 = mfma16(pa, *(const bf16x8*)(VT + swc(0  + col, ch)), o0);
    o1 = mfma16(pa, *(const bf16x8*)(VT + swc(16 + col, ch)), o1);
    o2 = mfma16(pa, *(const bf16x8*)(VT + swc(32 + col, ch)), o2);
  }

  float* ob = out + b * 3072 + (16 * w + 4 * qd) * 48 + col;
#pragma unroll
  for (int i = 0; i < 4; ++i) {  // rl for row t=16w+4qd+i lives at lane 4qd+i
    float rli = __shfl(rl, 4 * qd + i, 64);
    ob[i * 48 +  0] = o0[i] * rli;
    ob[i * 48 + 16] = o1[i] * rli;
    ob[i * 48 + 32] = o2[i] * rli;
  }
}

extern "C" void kernel_launch(void* const* d_in, const int* in_sizes, int n_in,
                              void* d_out, int out_size, void* d_ws, size_t ws_size,
                              hipStream_t stream) {
  const float* x  = (const float*)d_in[0];
  const float* Wq = (const float*)d_in[1];
  const float* Wk = (const float*)d_in[2];
  const float* Wv = (const float*)d_in[3];
  u16* wimg = (u16*)d_ws;  // 96*64 u16 = 12288 B
  head_prep<<<1, 256, 0, stream>>>(Wq, Wk, Wv, wimg);
  head_main<<<16384, 256, 0, stream>>>(x, wimg, (float*)d_out);
}

// Round 3
// 342.864 us; speedup vs baseline: 1.1042x; 1.1042x over previous
//
#include <hip/hip_runtime.h>
#include <math.h>

typedef __bf16 bf16x8 __attribute__((ext_vector_type(8)));
typedef float f32x4 __attribute__((ext_vector_type(4)));
typedef unsigned short u16;

__device__ __forceinline__ u16 f2b(float f) {
  // fp32 -> bf16 round-to-nearest-even (finite inputs only)
  unsigned u = __builtin_bit_cast(unsigned, f);
  u = (u + 0x7fffu + ((u >> 16) & 1u)) >> 16;
  return (u16)u;
}

__device__ __forceinline__ f32x4 mfma16(bf16x8 a, bf16x8 b, f32x4 c) {
  // D[i][j] = sum_k A[i][k]*B[j][k]; frag: lane holds OP[lane&15][8*(lane>>4)..+8)
  // per K=32 step; D: col=lane&15 -> j, row=4*(lane>>4)+reg -> i
  return __builtin_amdgcn_mfma_f32_16x16x32_bf16(a, b, c, 0, 0, 0);
}

// XOR-swizzled LDS addressing: tiles are [rows][64 u16], 16B chunk index XORed
// with (row & 7). Keeps every b128 access 16B-aligned AND spreads the LD=64
// (32-dword) row-stride aliasing across banks.
__device__ __forceinline__ int sw(int r, int c) {      // element (u16) address
  return (r << 6) + ((((c >> 3) ^ r) & 7) << 3) + (c & 7);
}
__device__ __forceinline__ int swc(int r, int ch) {    // chunk (16B) address
  return (r << 6) + (((ch ^ r) & 7) << 3);
}

// Prep: PRE-SWIZZLED bf16 weight image (rows of 64 u16, 12288 B):
//   rows 0-47:  M_t[c'][c] = scale * sum_h Wq[c][h]*Wk[c'][h]   ((scale*Wq@Wk^T)^T)
//   rows 48-95: Wv_t[h][c] = Wv[c][h]
// cols 48-63 zeroed (K pad; also serves as QM pad after the overlay).
// head_main stages this with 3 linear uint4 copies/thread -> LDS lands
// swizzled. (Round-2 tried reading fragments straight from global: 805 MB of
// scattered 16B L1 requests = +37 us L1-bound stall on the projection path.)
__global__ __launch_bounds__(256) void head_prep(const float* __restrict__ Wq,
                                                 const float* __restrict__ Wk,
                                                 const float* __restrict__ Wv,
                                                 u16* __restrict__ ws) {
  __shared__ float wq[2304], wk[2304], wv[2304];
  const float scale = 0.14433756729740643f;  // 1/sqrt(48)
  for (int i = threadIdx.x; i < 2304; i += 256) {
    wq[i] = Wq[i];
    wk[i] = Wk[i];
    wv[i] = Wv[i];
  }
  __syncthreads();
  for (int idx = threadIdx.x; idx < 96 * 64; idx += 256) {
    int r = idx >> 6, c = idx & 63;
    float v = 0.f;
    if (c < 48) {
      if (r < 48) {
        float a = 0.f;
        for (int h = 0; h < 48; ++h) a += wq[c * 48 + h] * wk[r * 48 + h];
        v = a * scale;
      } else {
        v = wv[c * 48 + (r - 48)];
      }
    }
    ws[sw(r, c)] = f2b(v);  // pre-swizzled
  }
}

// One workgroup (4 waves) per batch element; wave w owns t-rows [16w,16w+16).
// S is computed TRANSPOSED (S^T = X @ QM^T):
//  - QM produced as QM^T tiles -> vectorized ushort4 LDS writes
//  - softmax's reduction axis (s) is the D-fragment ROW axis: in-lane + 2 shuffles
//  - QM/P rows are wave-private (only own-row B/A-fragment reads) -> the QM
//    overlay (after sync2) and P overlay need only __threadfence_block.
// LDS (208 rows * 128 B = 26624 B -> 6 blocks/CU, 24 waves):
//   R0: rows 0-95 = WM(0-47) | WV(48-95); QM^T overlays rows 0-63 after sync2
//       (K-pad cols 48-63 inherited as zeros); P then overlays QM.
//   X : rows 96-159 (bf16 x, K-padded to 64)
//   VT: rows 160-207 (V transposed, h-major / s-inner)
__global__ __launch_bounds__(256, 6) void head_main(const float* __restrict__ x,
                                                    const u16* __restrict__ wimg,
                                                    float* __restrict__ out) {
  __shared__ u16 lds[208 * 64];
  u16* const R0 = lds;                 // weights, then QM/P (rows 0-63)
  u16* const X  = lds + 96 * 64;
  u16* const VT = lds + 160 * 64;

  const int tid  = threadIdx.x;
  const int lane = tid & 63;
  const int w    = tid >> 6;
  const int qd   = lane >> 4;
  const int col  = lane & 15;
  const long b   = blockIdx.x;

  // ---- stage weight image (bf16, pre-swizzled): 768 linear uint4 ----
  {
    const uint4* src = (const uint4*)wimg;
    uint4* dst = (uint4*)lds;
    dst[tid]       = src[tid];
    dst[tid + 256] = src[tid + 256];
    dst[tid + 512] = src[tid + 512];
  }
  // ---- stage OWN 16 x rows -> bf16 LDS (wave-contiguous float4 reads) ----
  {
    const float* xb = x + b * 3072 + w * 768;  // wave's 16 rows * 48 floats
#pragma unroll
    for (int it = 0; it < 3; ++it) {
      int e0 = lane * 4 + it * 256;   // element offset in the wave's 768 floats
      float4 v = *(const float4*)(xb + e0);
      int row = 16 * w + e0 / 48;
      int c0  = e0 % 48;              // multiple of 4 -> stays inside one chunk
      ushort4 pk;
      pk.x = f2b(v.x); pk.y = f2b(v.y); pk.z = f2b(v.z); pk.w = f2b(v.w);
      *(ushort4*)(X + sw(row, c0)) = pk;
    }
    // zero X K-pad (cols 48..63) of own rows: one ushort4 per thread
    ushort4 z = {0, 0, 0, 0};
    *(ushort4*)(X + sw(16 * w + col, 48 + 4 * qd)) = z;
  }
  __syncthreads();  // sync1: W + X staged

  // ---- own x fragments (A/B rows t = 16w+col) ----
  const int ar = 16 * w + col;
  const bf16x8 xa0 = *(const bf16x8*)(X + swc(ar, qd));
  const bf16x8 xa1 = *(const bf16x8*)(X + swc(ar, qd + 4));

  // ---- projections, weights from LDS ----
  // QM^T tile: D[c'][t] = sum_c M_t[c'][c] * x[t][c]  (M_t first operand)
  //   -> QM rows t=16w+col, cols c'=16n+4qd+i (held in aq[] until sync2)
  // V tile:    D[t][h]  = sum_c x[t][c] * Wv_t[h][c]
  //   -> VT[h=16n+col][s=16w+4qd+i], i consecutive -> ushort4
  f32x4 aq[3];
#pragma unroll
  for (int n = 0; n < 3; ++n) {
    const int mr = 16 * n + col;
    const bf16x8 m0 = *(const bf16x8*)(R0 + swc(mr, qd));
    const bf16x8 m1 = *(const bf16x8*)(R0 + swc(mr, qd + 4));
    const bf16x8 v0 = *(const bf16x8*)(R0 + swc(48 + mr, qd));
    const bf16x8 v1 = *(const bf16x8*)(R0 + swc(48 + mr, qd + 4));
    f32x4 a = {0.f, 0.f, 0.f, 0.f};
    a = mfma16(m0, xa0, a);
    a = mfma16(m1, xa1, a);
    aq[n] = a;
    f32x4 av = {0.f, 0.f, 0.f, 0.f};
    av = mfma16(xa0, v0, av);
    av = mfma16(xa1, v1, av);
    ushort4 pv;
    pv.x = f2b(av[0]); pv.y = f2b(av[1]); pv.z = f2b(av[2]); pv.w = f2b(av[3]);
    *(ushort4*)(VT + sw(16 * n + col, 16 * w + 4 * qd)) = pv;
  }

  __syncthreads();  // sync2: all W reads + VT writes complete; R0 becomes QM

  // ---- QM^T overlay write (own rows, vectorized) ----
#pragma unroll
  for (int n = 0; n < 3; ++n) {
    ushort4 pq;
    pq.x = f2b(aq[n][0]); pq.y = f2b(aq[n][1]);
    pq.z = f2b(aq[n][2]); pq.w = f2b(aq[n][3]);
    *(ushort4*)(R0 + sw(16 * w + col, 16 * n + 4 * qd)) = pq;
  }
  __threadfence_block();  // same-wave write->read ordering (wave-private rows)

  // ---- S^T = X @ QM^T : D[s=16st+4qd+i][t=16w+col] ----
  float sv[4][4];
  {
    const bf16x8 qb0 = *(const bf16x8*)(R0 + swc(ar, qd));
    const bf16x8 qb1 = *(const bf16x8*)(R0 + swc(ar, qd + 4));  // pad cols: zeros
#pragma unroll
    for (int st = 0; st < 4; ++st) {
      const int br = 16 * st + col;
      f32x4 a = {0.f, 0.f, 0.f, 0.f};
      a = mfma16(*(const bf16x8*)(X + swc(br, qd)), qb0, a);
      a = mfma16(*(const bf16x8*)(X + swc(br, qd + 4)), qb1, a);
#pragma unroll
      for (int i = 0; i < 4; ++i) sv[st][i] = a[i];
    }
  }

  // ---- causal mask + softmax over s (in-lane + 2 shuffles) ----
  const int tg = 16 * w + col;
  float m = -INFINITY;
#pragma unroll
  for (int st = 0; st < 4; ++st)
#pragma unroll
    for (int i = 0; i < 4; ++i) {
      int sg = 16 * st + 4 * qd + i;
      float v = (sg <= tg) ? sv[st][i] : -INFINITY;
      sv[st][i] = v;
      m = fmaxf(m, v);
    }
  m = fmaxf(m, __shfl_xor(m, 16, 64));
  m = fmaxf(m, __shfl_xor(m, 32, 64));
  float l = 0.f;
#pragma unroll
  for (int st = 0; st < 4; ++st)
#pragma unroll
    for (int i = 0; i < 4; ++i) {
      float p = __expf(sv[st][i] - m);  // exp(-inf)=0 handles the mask
      sv[st][i] = p;
      l += p;
    }
  l += __shfl_xor(l, 16, 64);
  l += __shfl_xor(l, 32, 64);
  float rl = __builtin_amdgcn_rcpf(l);  // per-lane: 1/l for t = 16w+col

  // ---- write P' (unnormalized) over QM: own rows, vectorized ----
#pragma unroll
  for (int st = 0; st < 4; ++st) {
    ushort4 pk;
    pk.x = f2b(sv[st][0]); pk.y = f2b(sv[st][1]);
    pk.z = f2b(sv[st][2]); pk.w = f2b(sv[st][3]);
    *(ushort4*)(R0 + sw(16 * w + col, 16 * st + 4 * qd)) = pk;
  }
  __threadfence_block();  // same-wave write->read ordering (wave-private rows)

  // ---- O = P' @ V (A = own P rows, B = VT rows), scale rows by 1/l ----
  f32x4 o0 = {0.f, 0.f, 0.f, 0.f}, o1 = o0, o2 = o0;
#pragma unroll
  for (int kt = 0; kt < 2; ++kt) {
    const int ch = qd + 4 * kt;
    bf16x8 pa = *(const bf16x8*)(R0 + swc(ar, ch));
    o0 = mfma16(pa, *(const bf16x8*)(VT + swc(0  + col, ch)), o0);
    o1 = mfma16(pa, *(const bf16x8*)(VT + swc(16 + col, ch)), o1);
    o2 = mfma16(pa, *(const bf16x8*)(VT + swc(32 + col, ch)), o2);
  }

  float* ob = out + b * 3072 + (16 * w + 4 * qd) * 48 + col;
#pragma unroll
  for (int i = 0; i < 4; ++i) {  // rl for row t=16w+4qd+i lives at lane 4qd+i
    float rli = __shfl(rl, 4 * qd + i, 64);
    ob[i * 48 +  0] = o0[i] * rli;
    ob[i * 48 + 16] = o1[i] * rli;
    ob[i * 48 + 32] = o2[i] * rli;
  }
}

extern "C" void kernel_launch(void* const* d_in, const int* in_sizes, int n_in,
                              void* d_out, int out_size, void* d_ws, size_t ws_size,
                              hipStream_t stream) {
  const float* x  = (const float*)d_in[0];
  const float* Wq = (const float*)d_in[1];
  const float* Wk = (const float*)d_in[2];
  const float* Wv = (const float*)d_in[3];
  u16* wimg = (u16*)d_ws;  // 96*64 u16 = 12288 B
  head_prep<<<1, 256, 0, stream>>>(Wq, Wk, Wv, wimg);
  head_main<<<16384, 256, 0, stream>>>(x, wimg, (float*)d_out);
}